// Round 1
// 463.089 us; speedup vs baseline: 3.7029x; 3.7029x over previous
//
#include <hip/hip_runtime.h>

#define T_TOK 4096
#define DDIM  1024
#define IDIM  2048
#define NE    8
#define TOTROWS 8192   // T_TOK * top_k

typedef unsigned short u16;
typedef unsigned int   u32;
typedef _Float16 f16;
typedef _Float16 f16x8 __attribute__((ext_vector_type(8)));
typedef _Float16 f16x4 __attribute__((ext_vector_type(4)));
typedef float    f32x16 __attribute__((ext_vector_type(16)));

// async global->LDS, 16B per lane; LDS dest is wave-uniform base + lane*16
static __device__ __forceinline__ void gload16(const f16* g, f16* l) {
  __builtin_amdgcn_global_load_lds(
      (const __attribute__((address_space(1))) void*)g,
      (__attribute__((address_space(3))) void*)l, 16, 0, 0);
}

// ---- conf[t][e] = sigmoid(dot(x[t], Wc[e]) + bc[e]); one wave per token ----
__global__ __launch_bounds__(256) void conf_kernel(
    const float* __restrict__ x, const float* __restrict__ Wc,
    const float* __restrict__ bc, float* __restrict__ conf)
{
  int gid  = blockIdx.x * 256 + threadIdx.x;
  int t    = gid >> 6;
  int lane = threadIdx.x & 63;
  if (t >= T_TOK) return;
  const float* xr = x + (size_t)t * DDIM;
  float acc[NE];
#pragma unroll
  for (int e = 0; e < NE; e++) acc[e] = 0.f;
  for (int d = lane; d < DDIM; d += 64) {
    float xv = xr[d];
#pragma unroll
    for (int e = 0; e < NE; e++) acc[e] += xv * Wc[e * DDIM + d];
  }
#pragma unroll
  for (int off = 32; off > 0; off >>= 1) {
#pragma unroll
    for (int e = 0; e < NE; e++) acc[e] += __shfl_down(acc[e], off, 64);
  }
  if (lane == 0) {
#pragma unroll
    for (int e = 0; e < NE; e++)
      conf[t * NE + e] = 1.f / (1.f + expf(-(acc[e] + bc[e])));
  }
}

// ---- one thread per token: top-2 by conf (ties -> lower index), softmax ----
__global__ __launch_bounds__(256) void top2_kernel(
    const float* __restrict__ conf,
    int* __restrict__ counts, int* __restrict__ list, float* __restrict__ wlist)
{
  int t = blockIdx.x * 256 + threadIdx.x;
  if (t >= T_TOK) return;
  float c[NE];
#pragma unroll
  for (int e = 0; e < NE; e++) c[e] = conf[t * NE + e];
  int i0 = 0;
#pragma unroll
  for (int e = 1; e < NE; e++) if (c[e] > c[i0]) i0 = e;
  int i1 = (i0 == 0) ? 1 : 0;
#pragma unroll
  for (int e = 0; e < NE; e++) if (e != i0 && c[e] > c[i1]) i1 = e;
  float w1 = 1.f / (1.f + expf(c[i0] - c[i1]));
  float w0 = 1.f - w1;
  int s0 = atomicAdd(&counts[i0], 1);
  list[i0 * T_TOK + s0]  = t;
  wlist[i0 * T_TOK + s0] = w0;
  int s1 = atomicAdd(&counts[i1], 1);
  list[i1 * T_TOK + s1]  = t;
  wlist[i1 * T_TOK + s1] = w1;
}

// ---- prefix sum over 8 experts ---------------------------------------------
__global__ void scan_kernel(const int* __restrict__ counts, int* __restrict__ base)
{
  if (threadIdx.x == 0 && blockIdx.x == 0) {
    int s = 0;
    for (int e = 0; e < NE; e++) { base[e] = s; s += counts[e]; }
    base[NE] = s;
  }
}

// ---- x fp32 -> fp16 ---------------------------------------------------------
__global__ __launch_bounds__(256) void cvt_x_kernel(
    const float* __restrict__ x, f16* __restrict__ xh)
{
  int i = blockIdx.x * 256 + threadIdx.x;        // 1 float4 per thread
  float4 v = ((const float4*)x)[i];
  f16x4 h; h[0] = (f16)v.x; h[1] = (f16)v.y; h[2] = (f16)v.z; h[3] = (f16)v.w;
  ((f16x4*)xh)[i] = h;
}

// ---- transpose+convert: in [R][C] fp32 -> out [C][R] fp16 (per expert z) ---
__global__ __launch_bounds__(256) void tpose_kernel(
    const float* __restrict__ in, f16* __restrict__ out, int R, int C)
{
  __shared__ float t[32][33];
  const size_t mat = (size_t)R * C;
  const float* src = in  + (size_t)blockIdx.z * mat;
  f16*         dst = out + (size_t)blockIdx.z * mat;
  int c0 = blockIdx.x * 32, r0 = blockIdx.y * 32;
  int tx = threadIdx.x & 31, ty = threadIdx.x >> 5;   // 32 x 8
#pragma unroll
  for (int i = 0; i < 32; i += 8)
    t[ty + i][tx] = src[(size_t)(r0 + ty + i) * C + c0 + tx];
  __syncthreads();
#pragma unroll
  for (int i = 0; i < 32; i += 8)
    dst[(size_t)(c0 + ty + i) * R + r0 + tx] = (f16)t[tx][ty + i];
}

// ---- MFMA GEMM config -------------------------------------------------------
// 128x128 tile, BK=64, 4 waves (2x2), each wave 64x64 out, mfma_f32_32x32x16_f16.
// LDS tiles [128 rows][64 k] f16, row stride 128B; 16B slots XOR-swizzled:
// phys_slot = data_slot ^ (row&7). global_load_lds writes linearly, so the
// inverse swizzle is applied on the per-lane GLOBAL source slot (rule #21).
constexpr int BM = 128, BN = 128, BK = 64;

// ---- GEMM1: h[slot][n] = silu(x@Wg)*(x@Wu)*w, fp16 out ---------------------
__global__ __launch_bounds__(256, 2) void gemm1_kernel(
    const f16* __restrict__ xh, const f16* __restrict__ WgT, const f16* __restrict__ WuT,
    const int* __restrict__ counts, const int* __restrict__ base,
    const int* __restrict__ list, const float* __restrict__ wlist,
    f16* __restrict__ hbuf)
{
  const int e   = blockIdx.z;
  const int cnt = counts[e];
  const int p0  = blockIdx.y * BM;
  if (p0 >= cnt) return;
  const int n0  = blockIdx.x * BN;

  __shared__ __align__(16) f16 As [BM * BK];
  __shared__ __align__(16) f16 Bgs[BN * BK];
  __shared__ __align__(16) f16 Bus[BN * BK];
  __shared__ int   tokS[BM];
  __shared__ float wS[BM];

  const int tid = threadIdx.x;
  if (tid < BM) {
    int p = p0 + tid;
    tokS[tid] = (p < cnt) ? list[e * T_TOK + p] : 0;
    wS[tid]   = (p < cnt) ? wlist[e * T_TOK + p] : 0.f;
  }
  __syncthreads();

  const int l  = tid & 63;
  const int w  = tid >> 6;          // wave id
  const int wr = w >> 1, wc = w & 1;
  const int rl = l >> 3;            // row within 8-row group
  const int sl = (l & 7) ^ rl;      // inverse-swizzled source slot
  const int lm = l & 31;
  const int kg = l >> 5;

  // staging source pointers: wave w handles insts i = 4w..4w+3 of each tile
  const f16* ga[4]; const f16* gg[4]; const f16* gu[4];
  const f16* WgE = WgT + ((size_t)e << 21);
  const f16* WuE = WuT + ((size_t)e << 21);
#pragma unroll
  for (int ii = 0; ii < 4; ii++) {
    int i = w * 4 + ii;
    int r = i * 8 + rl;
    ga[ii] = xh  + (size_t)tokS[r] * DDIM + sl * 8;
    gg[ii] = WgE + (size_t)(n0 + r) * DDIM + sl * 8;
    gu[ii] = WuE + (size_t)(n0 + r) * DDIM + sl * 8;
  }

  f32x16 accg[2][2], accu[2][2];
#pragma unroll
  for (int a = 0; a < 2; a++)
#pragma unroll
    for (int b = 0; b < 2; b++)
#pragma unroll
      for (int r = 0; r < 16; r++) { accg[a][b][r] = 0.f; accu[a][b][r] = 0.f; }

  for (int kt = 0; kt < DDIM / BK; kt++) {
    const int k0 = kt * BK;
#pragma unroll
    for (int ii = 0; ii < 4; ii++) {
      int i = w * 4 + ii;
      gload16(ga[ii] + k0, &As [i * 512]);
      gload16(gg[ii] + k0, &Bgs[i * 512]);
      gload16(gu[ii] + k0, &Bus[i * 512]);
    }
    __syncthreads();   // drains vmcnt: tiles staged; all waves done with prev tile
#pragma unroll
    for (int ks = 0; ks < 4; ks++) {
      f16x8 av[2], bg[2], bu[2];
#pragma unroll
      for (int mr = 0; mr < 2; mr++) {
        int R = wr * 64 + mr * 32 + lm;
        int slot = (ks * 2 + kg) ^ (R & 7);
        av[mr] = *(const f16x8*)&As[R * 64 + slot * 8];
      }
#pragma unroll
      for (int nc = 0; nc < 2; nc++) {
        int R = wc * 64 + nc * 32 + lm;
        int slot = (ks * 2 + kg) ^ (R & 7);
        bg[nc] = *(const f16x8*)&Bgs[R * 64 + slot * 8];
        bu[nc] = *(const f16x8*)&Bus[R * 64 + slot * 8];
      }
#pragma unroll
      for (int mr = 0; mr < 2; mr++)
#pragma unroll
        for (int nc = 0; nc < 2; nc++) {
          accg[mr][nc] = __builtin_amdgcn_mfma_f32_32x32x16_f16(av[mr], bg[nc], accg[mr][nc], 0, 0, 0);
          accu[mr][nc] = __builtin_amdgcn_mfma_f32_32x32x16_f16(av[mr], bu[nc], accu[mr][nc], 0, 0, 0);
        }
    }
    __syncthreads();
  }

  // epilogue: C/D layout col=lane&31, row=(reg&3)+8*(reg>>2)+4*(lane>>5)
  const int rowbase = base[e] + p0;
  const int rbase4  = kg * 4;
#pragma unroll
  for (int mr = 0; mr < 2; mr++)
#pragma unroll
    for (int nc = 0; nc < 2; nc++) {
      int ncol = n0 + wc * 64 + nc * 32 + lm;
#pragma unroll
      for (int r = 0; r < 16; r++) {
        int rin = (r & 3) + ((r >> 2) << 3) + rbase4;
        int p   = wr * 64 + mr * 32 + rin;
        if (p0 + p < cnt) {
          float g = accg[mr][nc][r], u = accu[mr][nc][r];
          float h = g / (1.f + expf(-g)) * u * wS[p];
          hbuf[(size_t)(rowbase + p) * IDIM + ncol] = (f16)h;
        }
      }
    }
}

// ---- GEMM2: out[tok,:] += h_row @ Wd[e]  (fp32 atomic combine) -------------
__global__ __launch_bounds__(256, 2) void gemm2_kernel(
    const f16* __restrict__ hbuf, const f16* __restrict__ WdT,
    const int* __restrict__ counts, const int* __restrict__ base,
    const int* __restrict__ list, float* __restrict__ out)
{
  const int e   = blockIdx.z;
  const int cnt = counts[e];
  const int p0  = blockIdx.y * BM;
  if (p0 >= cnt) return;
  const int n0  = blockIdx.x * BN;

  __shared__ __align__(16) f16 Hs [BM * BK];
  __shared__ __align__(16) f16 Bds[BN * BK];
  __shared__ int tokS[BM];

  const int tid = threadIdx.x;
  if (tid < BM) {
    int p = p0 + tid;
    tokS[tid] = (p < cnt) ? list[e * T_TOK + p] : 0;
  }
  __syncthreads();

  const int l  = tid & 63;
  const int w  = tid >> 6;
  const int wr = w >> 1, wc = w & 1;
  const int rl = l >> 3;
  const int sl = (l & 7) ^ rl;
  const int lm = l & 31;
  const int kg = l >> 5;

  const int rowbase = base[e] + p0;
  const f16* WdE = WdT + ((size_t)e << 21);

  const f16* ga[4]; const f16* gd[4];
#pragma unroll
  for (int ii = 0; ii < 4; ii++) {
    int i = w * 4 + ii;
    int r = i * 8 + rl;
    int hr = rowbase + r; if (hr > TOTROWS - 1) hr = TOTROWS - 1;  // last-expert pad clamp
    ga[ii] = hbuf + (size_t)hr * IDIM + sl * 8;
    gd[ii] = WdE  + (size_t)(n0 + r) * IDIM + sl * 8;
  }

  f32x16 acc[2][2];
#pragma unroll
  for (int a = 0; a < 2; a++)
#pragma unroll
    for (int b = 0; b < 2; b++)
#pragma unroll
      for (int r = 0; r < 16; r++) acc[a][b][r] = 0.f;

  for (int kt = 0; kt < IDIM / BK; kt++) {
    const int k0 = kt * BK;
#pragma unroll
    for (int ii = 0; ii < 4; ii++) {
      int i = w * 4 + ii;
      gload16(ga[ii] + k0, &Hs [i * 512]);
      gload16(gd[ii] + k0, &Bds[i * 512]);
    }
    __syncthreads();
#pragma unroll
    for (int ks = 0; ks < 4; ks++) {
      f16x8 av[2], bd[2];
#pragma unroll
      for (int mr = 0; mr < 2; mr++) {
        int R = wr * 64 + mr * 32 + lm;
        int slot = (ks * 2 + kg) ^ (R & 7);
        av[mr] = *(const f16x8*)&Hs[R * 64 + slot * 8];
      }
#pragma unroll
      for (int nc = 0; nc < 2; nc++) {
        int R = wc * 64 + nc * 32 + lm;
        int slot = (ks * 2 + kg) ^ (R & 7);
        bd[nc] = *(const f16x8*)&Bds[R * 64 + slot * 8];
      }
#pragma unroll
      for (int mr = 0; mr < 2; mr++)
#pragma unroll
        for (int nc = 0; nc < 2; nc++)
          acc[mr][nc] = __builtin_amdgcn_mfma_f32_32x32x16_f16(av[mr], bd[nc], acc[mr][nc], 0, 0, 0);
    }
    __syncthreads();
  }

  const int rbase4 = kg * 4;
#pragma unroll
  for (int mr = 0; mr < 2; mr++)
#pragma unroll
    for (int nc = 0; nc < 2; nc++) {
      int ncol = n0 + wc * 64 + nc * 32 + lm;
#pragma unroll
      for (int r = 0; r < 16; r++) {
        int rin = (r & 3) + ((r >> 2) << 3) + rbase4;
        int p   = wr * 64 + mr * 32 + rin;
        if (p0 + p < cnt)
          atomicAdd(&out[(size_t)tokS[p] * DDIM + ncol], acc[mr][nc][r]);
      }
    }
}

// ---- launch -----------------------------------------------------------------
extern "C" void kernel_launch(void* const* d_in, const int* in_sizes, int n_in,
                              void* d_out, int out_size, void* d_ws, size_t ws_size,
                              hipStream_t stream)
{
  const float* x  = (const float*)d_in[0];
  const float* Wc = (const float*)d_in[1];
  const float* bc = (const float*)d_in[2];
  const float* Wg = (const float*)d_in[3];
  const float* Wu = (const float*)d_in[4];
  const float* Wd = (const float*)d_in[5];
  float* out = (float*)d_out;

  char* ws = (char*)d_ws;
  int*   counts = (int*)(ws + 0);              // 64 B
  int*   base   = (int*)(ws + 256);            // 36 B
  float* conf   = (float*)(ws + 1024);         // 128 KiB -> 132096
  int*   list   = (int*)(ws + 132096);         // 128 KiB -> 263168
  float* wlist  = (float*)(ws + 263168);       // 128 KiB -> 394240
  f16*   xh     = (f16*)(ws + 394240);         // 8 MiB   -> 8782848
  f16*   hbuf   = (f16*)(ws + 8782848);        // 32 MiB  -> 42337280
  f16*   W1     = (f16*)(ws + 42337280);       // 32 MiB  -> 75891712  (WgT, then WdT)
  f16*   W2     = (f16*)(ws + 75891712);       // 32 MiB  -> 109446144 (WuT)

  hipMemsetAsync(counts, 0, 64, stream);
  hipMemsetAsync(out, 0, (size_t)out_size * sizeof(float), stream);

  conf_kernel<<<T_TOK / 4, 256, 0, stream>>>(x, Wc, bc, conf);
  top2_kernel<<<T_TOK / 256, 256, 0, stream>>>(conf, counts, list, wlist);
  scan_kernel<<<1, 64, 0, stream>>>(counts, base);

  cvt_x_kernel<<<T_TOK * DDIM / 1024, 256, 0, stream>>>(x, xh);
  dim3 gt1(IDIM / 32, DDIM / 32, NE);
  tpose_kernel<<<gt1, 256, 0, stream>>>(Wg, W1, DDIM, IDIM);  // WgT [I][D]
  tpose_kernel<<<gt1, 256, 0, stream>>>(Wu, W2, DDIM, IDIM);  // WuT [I][D]

  dim3 g1(IDIM / BN, T_TOK / BM, NE);
  gemm1_kernel<<<g1, 256, 0, stream>>>(xh, W1, W2, counts, base, list, wlist, hbuf);

  dim3 gt2(DDIM / 32, IDIM / 32, NE);
  tpose_kernel<<<gt2, 256, 0, stream>>>(Wd, W1, IDIM, DDIM);  // WdT [D][I], reuse W1

  dim3 g2(DDIM / BN, T_TOK / BM, NE);
  gemm2_kernel<<<g2, 256, 0, stream>>>(hbuf, W1, counts, base, list, out);
}